// Round 3
// baseline (1559.653 us; speedup 1.0000x reference)
//
#include <hip/hip_runtime.h>
#include <math.h>

// VMD: T = 2^20, K = 3, 50 iterations.
// Workspace layout (~24.2 MB):
//   [0,8MB)     f_hat  (float2, s-layout: s = k1*1024+k2, t(s) = ((k2^512)<<10)|k1)
//   [8,16MB)    h = f_hat - lam/2 at the kept iteration (float2, s-layout)
//   [16,24MB)   scratch (float2)  -- FFT intermediate; fallback path's lam aliases this
//   [24MB..)    shadow acc: persistent: double[50][32 copies][8]; fallback: double[8][64]
//   +112KB      omega0: float[16]; omegaF: float[16]; barrier: unsigned[64]
// Fallback lam_old lives in d_out (dead until inverse passes overwrite it).

#define ALPHA_F 2000.0f
#define TAU_F   1e-7f

static __device__ __forceinline__ int lpad(int i) { return i + (i >> 5); }
static __device__ __forceinline__ int swz(int i)  { return ((i & 7) << 7) | (i >> 3); }

#define PADN 1057

// ---------------- 1024-point radix-4 Stockham FFT in LDS ----------------
template<int SIGN>   // -1 = forward (e^{-i}), +1 = inverse (e^{+i}, unscaled)
static __device__ void fft1024(float* Ar, float* Ai, float* Br, float* Bi)
{
  const int u = threadIdx.x;
#pragma unroll
  for (int st = 0; st < 5; ++st) {
    float *ir, *ii, *pr, *pi;
    if (st & 1) { ir = Br; ii = Bi; pr = Ar; pi = Ai; }
    else        { ir = Ar; ii = Ai; pr = Br; pi = Bi; }
    const int quarter = 1 << (2 * st);
    const int p = u & (quarter - 1);
    const int g = u >> (2 * st);

    float sw, cw;
    sincospif((float)(2 * p) * (1.0f / (float)(4 << (2 * st))), &sw, &cw);
    const float w1r = cw,                 w1i = (SIGN < 0) ? -sw : sw;
    const float w2r = w1r*w1r - w1i*w1i,  w2i = 2.0f*w1r*w1i;
    const float w3r = w2r*w1r - w2i*w1i,  w3i = w2r*w1i + w2i*w1r;

    float x0r = ir[lpad(u      )], x0i = ii[lpad(u      )];
    float x1r = ir[lpad(u + 256)], x1i = ii[lpad(u + 256)];
    float x2r = ir[lpad(u + 512)], x2i = ii[lpad(u + 512)];
    float x3r = ir[lpad(u + 768)], x3i = ii[lpad(u + 768)];

    float y1r = x1r*w1r - x1i*w1i, y1i = x1r*w1i + x1i*w1r;
    float y2r = x2r*w2r - x2i*w2i, y2i = x2r*w2i + x2i*w2r;
    float y3r = x3r*w3r - x3i*w3i, y3i = x3r*w3i + x3i*w3r;

    float t0r = x0r + y2r, t0i = x0i + y2i;
    float t1r = x0r - y2r, t1i = x0i - y2i;
    float t2r = y1r + y3r, t2i = y1i + y3i;
    float t3r = y1r - y3r, t3i = y1i - y3i;

    float o0r = t0r + t2r, o0i = t0i + t2i;
    float o2r = t0r - t2r, o2i = t0i - t2i;
    float o1r, o1i, o3r, o3i;
    if (SIGN < 0) {
      o1r = t1r + t3i; o1i = t1i - t3r;
      o3r = t1r - t3i; o3i = t1i + t3r;
    } else {
      o1r = t1r - t3i; o1i = t1i + t3r;
      o3r = t1r + t3i; o3i = t1i - t3r;
    }
    const int base = (g << (2 * st + 2)) + p;
    pr[lpad(base              )] = o0r; pi[lpad(base              )] = o0i;
    pr[lpad(base +     quarter)] = o1r; pi[lpad(base +     quarter)] = o1i;
    pr[lpad(base + 2 * quarter)] = o2r; pi[lpad(base + 2 * quarter)] = o2i;
    pr[lpad(base + 3 * quarter)] = o3r; pi[lpad(base + 3 * quarter)] = o3i;
    __syncthreads();
  }
}

// ---------------- init ----------------
__global__ __launch_bounds__(256) void k_init(double* shadow, float* omega0,
                                              unsigned* bar,
                                              const float* __restrict__ omega_init)
{
  int g = blockIdx.x * 256 + threadIdx.x;
  for (int j = g; j < 12800; j += 64 * 256) shadow[j] = 0.0;
  if (g < 64) bar[g] = 0u;
  if (g < 3) omega0[g] = omega_init[g];
}

// ---------------- forward FFT ----------------
__global__ __launch_bounds__(256) void k_fwd_passA(const float* __restrict__ x,
                                                   float2* __restrict__ ws0)
{
  __shared__ float Ar[PADN], Ai[PADN], Br[PADN], Bi[PADN];
  const int b = swz(blockIdx.x);   // n2
  const int tid = threadIdx.x;
#pragma unroll
  for (int q = 0; q < 4; ++q) {
    int j = tid + 256 * q;         // n1
    Ar[lpad(j)] = x[(size_t)j * 1024 + b];
    Ai[lpad(j)] = 0.0f;
  }
  __syncthreads();
  fft1024<-1>(Ar, Ai, Br, Bi);
#pragma unroll
  for (int q = 0; q < 4; ++q) {
    int k1 = tid + 256 * q;
    int ph = b * k1;               // < 2^20, exact in fp32
    float s, c;
    sincospif((float)ph * (2.0f / 1048576.0f), &s, &c);
    float vr = Br[lpad(k1)], vi = Bi[lpad(k1)];
    ws0[(size_t)b * 1024 + k1] = make_float2(vr * c + vi * s, vi * c - vr * s);
  }
}

__global__ __launch_bounds__(256) void k_fwd_passB(const float2* __restrict__ ws0,
                                                   float2* __restrict__ fhat)
{
  __shared__ float Ar[PADN], Ai[PADN], Br[PADN], Bi[PADN];
  const int b = swz(blockIdx.x);   // k1
  const int tid = threadIdx.x;
#pragma unroll
  for (int q = 0; q < 4; ++q) {
    int j = tid + 256 * q;         // n2
    float2 v = ws0[(size_t)j * 1024 + b];
    Ar[lpad(j)] = v.x; Ai[lpad(j)] = v.y;
  }
  __syncthreads();
  fft1024<-1>(Ar, Ai, Br, Bi);
#pragma unroll
  for (int q = 0; q < 4; ++q) {
    int k2 = tid + 256 * q;
    fhat[(size_t)b * 1024 + k2] = make_float2(Br[lpad(k2)], Bi[lpad(k2)]);
  }
}

// ---------------- hand-rolled grid barrier (no cooperative-groups machinery) ----
static __device__ __forceinline__ void grid_barrier(unsigned* cnt, unsigned* gen,
                                                    unsigned nblocks)
{
  __syncthreads();
  if (threadIdx.x == 0) {
    unsigned g = __hip_atomic_load(gen, __ATOMIC_RELAXED, __HIP_MEMORY_SCOPE_AGENT);
    unsigned arrived = __hip_atomic_fetch_add(cnt, 1u, __ATOMIC_ACQ_REL,
                                              __HIP_MEMORY_SCOPE_AGENT);
    if (arrived == nblocks - 1) {
      __hip_atomic_store(cnt, 0u, __ATOMIC_RELAXED, __HIP_MEMORY_SCOPE_AGENT);
      __hip_atomic_store(gen, g + 1u, __ATOMIC_RELEASE, __HIP_MEMORY_SCOPE_AGENT);
    } else {
      while (__hip_atomic_load(gen, __ATOMIC_ACQUIRE, __HIP_MEMORY_SCOPE_AGENT) == g)
        __builtin_amdgcn_s_sleep(2);
    }
  }
  __syncthreads();
}

// ---------------- persistent 50-iteration kernel ----------------
// NQ float4s (= 2*NQ complex) per thread; grid = 524288/(256*NQ) blocks of 256.
template<int NQ>
__global__ __launch_bounds__(256, (NQ == 4) ? 2 : 1) void k_vmd_persist(
    const float2* __restrict__ fhat, float2* __restrict__ h_out,
    const float* __restrict__ omega0, float* __restrict__ omega_final,
    double* __restrict__ shadow, unsigned* bar)
{
  const int NT = 524288 / NQ;                // total threads = float4 stride
  const int tid = threadIdx.x;
  const int bid = blockIdx.x;
  const int gthread = bid * 256 + tid;
  const unsigned nblocks = (unsigned)(NT / 256);

  __shared__ float  sb[8];
  __shared__ double red[256];

  float4 f[NQ], lam[NQ], lamp[NQ];
  float  frq[NQ][2];
#pragma unroll
  for (int q = 0; q < NQ; ++q) {
    const int f4i = gthread + q * NT;        // coalesced grid-stride
    f[q] = ((const float4*)fhat)[f4i];
    lam[q] = make_float4(0.f, 0.f, 0.f, 0.f);
    lamp[q] = lam[q];
#pragma unroll
    for (int c = 0; c < 2; ++c) {
      const int s = f4i * 2 + c;
      const int tt = (((s & 1023) ^ 512) << 10) | (s >> 10);
      frq[q][c] = (float)tt * (1.0f / 1048576.0f) - 0.5f;
    }
  }
  if (tid == 0) { sb[0] = omega0[0]; sb[1] = omega0[1]; sb[2] = omega0[2]; }
  __syncthreads();
  float om0 = sb[0], om1 = sb[1], om2 = sb[2];
  float pm0 = 0.f, pm1 = 0.f, pm2 = 0.f;
  const float TAU2 = TAU_F * TAU_F;

  for (int n = 0; n < 50; ++n) {
    const bool check = (n % 10 == 0) && (n > 0);
    const bool snap  = (n % 10) == 9;
    const bool hw    = check || (n == 49);   // freeze-candidate entry

    if (snap) {
#pragma unroll
      for (int q = 0; q < NQ; ++q) lamp[q] = lam[q];
      pm0 = om0; pm1 = om1; pm2 = om2;
    }
    if (hw) {
#pragma unroll
      for (int q = 0; q < NQ; ++q) {
        const int f4i = gthread + q * NT;
        float4 hv;
        hv.x = f[q].x - 0.5f * lam[q].x; hv.y = f[q].y - 0.5f * lam[q].y;
        hv.z = f[q].z - 0.5f * lam[q].z; hv.w = f[q].w - 0.5f * lam[q].w;
        ((float4*)h_out)[f4i] = hv;
      }
      if (gthread == 0) {
        omega_final[0] = om0; omega_final[1] = om1; omega_final[2] = om2;
      }
    }

    double p0 = 0, p1 = 0, p2 = 0, p3 = 0, p4 = 0, p5 = 0, p6 = 0, p7 = 0;
#pragma unroll
    for (int q = 0; q < NQ; ++q) {
#pragma unroll
      for (int c = 0; c < 2; ++c) {
        const float fr = c ? f[q].z : f[q].x,     fi = c ? f[q].w : f[q].y;
        const float lr = c ? lam[q].z : lam[q].x, li = c ? lam[q].w : lam[q].y;
        const float freq = frq[q][c];
        float a0 = freq - om0, a1 = freq - om1, a2 = freq - om2;
        float d0 = a0 * a0, d1 = a1 * a1, d2 = a2 * a2;
        float w0 = 1.0f / (1.0f + ALPHA_F * (d0 + d1 + TAU2));
        float w1 = 1.0f / (1.0f + ALPHA_F * (d0 + d1 + d2 + TAU2));
        float w2 = 1.0f / (1.0f + ALPHA_F * (d1 + d2 + TAU2));
        float hr = fr - 0.5f * lr, hi = fi - 0.5f * li;
        float g = hr * hr + hi * hi;
        float gw0 = g * w0 * w0, gw1 = g * w1 * w1, gw2 = g * w2 * w2;
        p0 += (double)(freq * gw0); p1 += (double)(freq * gw1); p2 += (double)(freq * gw2);
        p3 += (double)gw0;          p4 += (double)gw1;          p5 += (double)gw2;
        float S = w0 + w1 + w2;
        float nlr = lr + TAU_F * (hr * S - fr);
        float nli = li + TAU_F * (hi * S - fi);
        if (c == 0) { lam[q].x = nlr; lam[q].y = nli; }
        else        { lam[q].z = nlr; lam[q].w = nli; }
        if (check) {
          const float plr = c ? lamp[q].z : lamp[q].x, pli = c ? lamp[q].w : lamp[q].y;
          float hpr = fr - 0.5f * plr, hpi = fi - 0.5f * pli;
          float b0 = freq - pm0, b1 = freq - pm1, b2 = freq - pm2;
          float e0 = b0 * b0, e1 = b1 * b1, e2 = b2 * b2;
          float v0 = 1.0f / (1.0f + ALPHA_F * (e0 + e1 + TAU2));
          float v1 = 1.0f / (1.0f + ALPHA_F * (e0 + e1 + e2 + TAU2));
          float v2 = 1.0f / (1.0f + ALPHA_F * (e1 + e2 + TAU2));
          float dr, di;
          dr = hr * w0 - hpr * v0; di = hi * w0 - hpi * v0; p6 += (double)(dr * dr + di * di);
          dr = hr * w1 - hpr * v1; di = hi * w1 - hpi * v1; p6 += (double)(dr * dr + di * di);
          dr = hr * w2 - hpr * v2; di = hi * w2 - hpi * v2; p6 += (double)(dr * dr + di * di);
          float gp = hpr * hpr + hpi * hpi;
          p7 += (double)(gp * (v0 * v0 + v1 * v1 + v2 * v2));
        }
      }
    }

    // block-level reduce: wave shuffle -> LDS -> 8 partials -> shadow atomics
    {
      double pv[8] = { p0, p1, p2, p3, p4, p5, p6, p7 };
      const int lane = tid & 63, wv = tid >> 6;
#pragma unroll
      for (int j = 0; j < 8; ++j) {
        double v = pv[j];
        for (int off = 32; off; off >>= 1) v += __shfl_down(v, off, 64);
        if (lane == 0) red[wv * 8 + j] = v;
      }
    }
    __syncthreads();
    if (tid < 8) {
      double s = red[tid] + red[8 + tid] + red[16 + tid] + red[24 + tid];
      unsafeAtomicAdd(&shadow[(size_t)n * 256 + (size_t)(bid & 31) * 8 + tid], s);
    }

    grid_barrier(bar, bar + 32, nblocks);

    // gather: 32 copies x 8 slots -> 8 sums (identical order in every block)
    red[tid] = __hip_atomic_load(&shadow[(size_t)n * 256 + tid], __ATOMIC_RELAXED,
                                 __HIP_MEMORY_SCOPE_AGENT);
    __syncthreads();
#pragma unroll
    for (int s = 128; s >= 8; s >>= 1) {
      if (tid < s) red[tid] += red[tid + s];
      __syncthreads();
    }
    if (tid == 0) {
      float no0 = (float)(red[0] / red[3]);
      float no1 = (float)(red[1] / red[4]);
      float no2 = (float)(red[2] / red[5]);
      float conv = 0.0f;
      if (check) {
        bool ud_ok = red[6] < 1e-6 * red[7];
        float omd = (fabsf(no0 - no2) + fabsf(no1 - no0) + fabsf(no2 - no1)) * (1.0f / 3.0f);
        if (ud_ok && omd < 1e-6f) conv = 1.0f;
      }
      sb[0] = no0; sb[1] = no1; sb[2] = no2; sb[3] = conv;
    }
    __syncthreads();
    om0 = sb[0]; om1 = sb[1]; om2 = sb[2];
    if (sb[3] != 0.0f) break;   // grid-uniform: identical sums in every block
  }
}

// ---------------- fallback: round-1 proven per-iteration kernel ----------------
static __device__ __forceinline__ bool conv_at(const double* __restrict__ acc, int m)
{
  double a6 = acc[6 * 64 + m], a7 = acc[7 * 64 + m];
  if (!(a6 < 1e-6 * a7)) return false;
  float o0 = (float)(acc[0 * 64 + m] / acc[3 * 64 + m]);
  float o1 = (float)(acc[1 * 64 + m] / acc[4 * 64 + m]);
  float o2 = (float)(acc[2 * 64 + m] / acc[5 * 64 + m]);
  float omd = (fabsf(o0 - o2) + fabsf(o1 - o0) + fabsf(o2 - o1)) * (1.0f / 3.0f);
  return omd < 1e-6f;
}

__global__ __launch_bounds__(256) void k_vmd_iter(
    const float2* __restrict__ fhat, float2* __restrict__ lam,
    float2* __restrict__ lam_old, const float* __restrict__ omega0,
    double* __restrict__ acc, float2* __restrict__ h_out,
    float* __restrict__ omega_final, int n)
{
  __shared__ float sb[8];
  __shared__ double red[32];
  const int tid = threadIdx.x;
  const bool check = (n > 0) && (n % 10 == 0);
  const bool wold  = ((n % 10) == 9) || check;
  const bool hw    = check || (n == 49);
  const bool first = (n == 0);

  if (tid == 0) {
    bool done = false;
    for (int m = 10; m < n; m += 10) if (conv_at(acc, m)) { done = true; break; }
    if (first) { sb[0] = omega0[0]; sb[1] = omega0[1]; sb[2] = omega0[2]; }
    else {
      sb[0] = (float)(acc[0 * 64 + n - 1] / acc[3 * 64 + n - 1]);
      sb[1] = (float)(acc[1 * 64 + n - 1] / acc[4 * 64 + n - 1]);
      sb[2] = (float)(acc[2 * 64 + n - 1] / acc[5 * 64 + n - 1]);
    }
    if (check) {
      sb[3] = (float)(acc[0 * 64 + n - 2] / acc[3 * 64 + n - 2]);
      sb[4] = (float)(acc[1 * 64 + n - 2] / acc[4 * 64 + n - 2]);
      sb[5] = (float)(acc[2 * 64 + n - 2] / acc[5 * 64 + n - 2]);
    } else { sb[3] = 0.f; sb[4] = 0.f; sb[5] = 0.f; }
    sb[6] = done ? 1.0f : 0.0f;
  }
  __syncthreads();
  if (sb[6] != 0.0f) return;   // frozen
  const float om0 = sb[0], om1 = sb[1], om2 = sb[2];
  const float pm0 = sb[3], pm1 = sb[4], pm2 = sb[5];
  if (hw && blockIdx.x == 0 && tid == 0) {
    omega_final[0] = om0; omega_final[1] = om1; omega_final[2] = om2;
  }

  const float TAU2 = TAU_F * TAU_F;
  double p0 = 0, p1 = 0, p2 = 0, p3 = 0, p4 = 0, p5 = 0, p6 = 0, p7 = 0;
  const int gid = blockIdx.x * 256 + tid;

#pragma unroll
  for (int h2 = 0; h2 < 2; ++h2) {
    const int f4i = gid * 2 + h2;
    const float4 fv = ((const float4*)fhat)[f4i];
    float4 lv;
    if (first) lv = make_float4(0.f, 0.f, 0.f, 0.f);
    else       lv = ((const float4*)lam)[f4i];
    float4 lov = make_float4(0.f, 0.f, 0.f, 0.f);
    if (check)  lov = ((const float4*)lam_old)[f4i];
    if (hw) {
      float4 hv;
      hv.x = fv.x - 0.5f * lv.x; hv.y = fv.y - 0.5f * lv.y;
      hv.z = fv.z - 0.5f * lv.z; hv.w = fv.w - 0.5f * lv.w;
      ((float4*)h_out)[f4i] = hv;
    }
    float4 nl;
#pragma unroll
    for (int c = 0; c < 2; ++c) {
      const int s = f4i * 2 + c;
      const float fr = c ? fv.z : fv.x, fi = c ? fv.w : fv.y;
      const float lr = c ? lv.z : lv.x, li = c ? lv.w : lv.y;
      const int k2s = s & 1023, k1s = s >> 10;
      const int tt = ((k2s ^ 512) << 10) | k1s;
      const float freq = (float)tt * (1.0f / 1048576.0f) - 0.5f;
      float a0 = freq - om0, a1 = freq - om1, a2 = freq - om2;
      float d0 = a0 * a0, d1 = a1 * a1, d2 = a2 * a2;
      float w0 = 1.0f / (1.0f + ALPHA_F * (d0 + d1 + TAU2));
      float w1 = 1.0f / (1.0f + ALPHA_F * (d0 + d1 + d2 + TAU2));
      float w2 = 1.0f / (1.0f + ALPHA_F * (d1 + d2 + TAU2));
      float hr = fr - 0.5f * lr, hi = fi - 0.5f * li;
      float g = hr * hr + hi * hi;
      float gw0 = g * w0 * w0, gw1 = g * w1 * w1, gw2 = g * w2 * w2;
      p0 += (double)(freq * gw0); p1 += (double)(freq * gw1); p2 += (double)(freq * gw2);
      p3 += (double)gw0;          p4 += (double)gw1;          p5 += (double)gw2;
      float S = w0 + w1 + w2;
      float nlr = lr + TAU_F * (hr * S - fr);
      float nli = li + TAU_F * (hi * S - fi);
      if (c == 0) { nl.x = nlr; nl.y = nli; } else { nl.z = nlr; nl.w = nli; }
      if (check) {
        const float plr = c ? lov.z : lov.x, pli = c ? lov.w : lov.y;
        float hpr = fr - 0.5f * plr, hpi = fi - 0.5f * pli;
        float b0 = freq - pm0, b1 = freq - pm1, b2 = freq - pm2;
        float e0 = b0 * b0, e1 = b1 * b1, e2 = b2 * b2;
        float v0 = 1.0f / (1.0f + ALPHA_F * (e0 + e1 + TAU2));
        float v1 = 1.0f / (1.0f + ALPHA_F * (e0 + e1 + e2 + TAU2));
        float v2 = 1.0f / (1.0f + ALPHA_F * (e1 + e2 + TAU2));
        float dr, di;
        dr = hr * w0 - hpr * v0; di = hi * w0 - hpi * v0; p6 += (double)(dr * dr + di * di);
        dr = hr * w1 - hpr * v1; di = hi * w1 - hpi * v1; p6 += (double)(dr * dr + di * di);
        dr = hr * w2 - hpr * v2; di = hi * w2 - hpi * v2; p6 += (double)(dr * dr + di * di);
        float gp = hpr * hpr + hpi * hpi;
        p7 += (double)(gp * (v0 * v0 + v1 * v1 + v2 * v2));
      }
    }
    ((float4*)lam)[f4i] = nl;
    if (wold) ((float4*)lam_old)[f4i] = lv;
  }

  {
    double pv[8] = { p0, p1, p2, p3, p4, p5, p6, p7 };
    const int lane = tid & 63, wv = tid >> 6;
#pragma unroll
    for (int j = 0; j < 8; ++j) {
      double v = pv[j];
      for (int off = 32; off; off >>= 1) v += __shfl_down(v, off, 64);
      if (lane == 0) red[wv * 8 + j] = v;
    }
  }
  __syncthreads();
  if (tid < 8) {
    double ssum = red[tid] + red[8 + tid] + red[16 + tid] + red[24 + tid];
    unsafeAtomicAdd(&acc[tid * 64 + n], ssum);
  }
}

// ---------------- inverse FFT (per mode) ----------------
__global__ __launch_bounds__(256) void k_inv_passA(
    const float2* __restrict__ h, const float* __restrict__ omega_final,
    float2* __restrict__ ws0, int mode)
{
  __shared__ float Ar[PADN], Ai[PADN], Br[PADN], Bi[PADN];
  __shared__ float som[3];
  const int tid = threadIdx.x;
  if (tid == 0) { som[0] = omega_final[0]; som[1] = omega_final[1]; som[2] = omega_final[2]; }
  __syncthreads();
  const float om0 = som[0], om1 = som[1], om2 = som[2];
  const int b = swz(blockIdx.x);   // n2
  const float TAU2 = TAU_F * TAU_F;
#pragma unroll
  for (int q = 0; q < 4; ++q) {
    int j = tid + 256 * q;         // n1 ; ifftshift cancels: contiguous load
    float2 hv = h[(size_t)b * 1024 + j];
    int tt = ((j ^ 512) << 10) | b;
    float freq = (float)tt * (1.0f / 1048576.0f) - 0.5f;
    float a0 = freq - om0, a1 = freq - om1, a2 = freq - om2;
    float d0 = a0 * a0, d1 = a1 * a1, d2 = a2 * a2;
    float den = (mode == 0) ? (d0 + d1) : (mode == 1) ? (d0 + d1 + d2) : (d1 + d2);
    float wk = 1.0f / (1.0f + ALPHA_F * (den + TAU2));
    Ar[lpad(j)] = hv.x * wk; Ai[lpad(j)] = hv.y * wk;
  }
  __syncthreads();
  fft1024<1>(Ar, Ai, Br, Bi);
#pragma unroll
  for (int q = 0; q < 4; ++q) {
    int m1 = tid + 256 * q;
    int ph = b * m1;
    float s, c;
    sincospif((float)ph * (2.0f / 1048576.0f), &s, &c);
    float vr = Br[lpad(m1)], vi = Bi[lpad(m1)];
    ws0[(size_t)b * 1024 + m1] = make_float2(vr * c - vi * s, vi * c + vr * s);
  }
}

__global__ __launch_bounds__(256) void k_inv_passB(const float2* __restrict__ ws0,
                                                   float* __restrict__ out)
{
  __shared__ float Ar[PADN], Ai[PADN], Br[PADN], Bi[PADN];
  const int b = swz(blockIdx.x);   // m1
  const int tid = threadIdx.x;
#pragma unroll
  for (int q = 0; q < 4; ++q) {
    int j = tid + 256 * q;         // n2
    float2 v = ws0[(size_t)j * 1024 + b];
    Ar[lpad(j)] = v.x; Ai[lpad(j)] = v.y;
  }
  __syncthreads();
  fft1024<1>(Ar, Ai, Br, Bi);
#pragma unroll
  for (int q = 0; q < 4; ++q) {
    int m2 = tid + 256 * q;
    out[(size_t)m2 * 1024 + b] = Br[lpad(m2)] * (1.0f / 1048576.0f);
  }
}

// ---------------- host launch ----------------
extern "C" void kernel_launch(void* const* d_in, const int* in_sizes, int n_in,
                              void* d_out, int out_size, void* d_ws, size_t ws_size,
                              hipStream_t stream)
{
  (void)in_sizes; (void)n_in; (void)out_size; (void)ws_size;
  const float* x       = (const float*)d_in[0];
  const float* om_init = (const float*)d_in[1];
  float* out = (float*)d_out;

  char* w = (char*)d_ws;
  const size_t MB = 1024ull * 1024ull;
  float2*   fhat    = (float2*)(w);
  float2*   h       = (float2*)(w + 8 * MB);
  float2*   scratch = (float2*)(w + 16 * MB);
  double*   shadow  = (double*)(w + 24 * MB);              // 12800 doubles
  float*    omega0  = (float*)(w + 24 * MB + 112 * 1024);
  float*    omegaF  = omega0 + 16;
  unsigned* bar     = (unsigned*)(w + 24 * MB + 112 * 1024 + 256);

  k_init<<<64, 256, 0, stream>>>(shadow, omega0, bar, om_init);
  k_fwd_passA<<<1024, 256, 0, stream>>>(x, scratch);
  k_fwd_passB<<<1024, 256, 0, stream>>>(scratch, fhat);

  {
    void* p0 = (void*)fhat;   void* p1 = (void*)h;
    void* p2 = (void*)omega0; void* p3 = (void*)omegaF;
    void* p4 = (void*)shadow; void* p5 = (void*)bar;
    void* args[6] = { &p0, &p1, &p2, &p3, &p4, &p5 };

    hipError_t e = hipLaunchCooperativeKernel((void*)&k_vmd_persist<4>, dim3(512),
                                              dim3(256), args, 0, stream);
    if (e != hipSuccess) {
      (void)hipGetLastError();
      e = hipLaunchCooperativeKernel((void*)&k_vmd_persist<8>, dim3(256),
                                     dim3(256), args, 0, stream);
    }
    if (e != hipSuccess) {
      (void)hipGetLastError();
      // Proven round-1 path: lam aliases FFT scratch; lam_old lives in d_out
      // (dead until the inverse passes fully overwrite it).
      float2* lam     = scratch;
      float2* lam_old = (float2*)d_out;
      for (int n = 0; n < 50; ++n)
        k_vmd_iter<<<1024, 256, 0, stream>>>(fhat, lam, lam_old, omega0,
                                             shadow, h, omegaF, n);
    }
  }

  for (int mode = 0; mode < 3; ++mode) {
    k_inv_passA<<<1024, 256, 0, stream>>>(h, omegaF, scratch, mode);
    k_inv_passB<<<1024, 256, 0, stream>>>(scratch, out + (size_t)mode * 1048576ull);
  }
}